// Round 1
// baseline (76.276 us; speedup 1.0000x reference)
//
#include <hip/hip_runtime.h>

// TauLoss: 1 - mean_c [ sum_{i,j} sign(y[c,i]-y[c,j]) * tanh(p[c,i]-p[c,j]) / (N*(N-1)) ]
//
// Identities:
//   tanh(d*s) = s*tanh(d), s in {-1,0,1}
//   tanh(a-b) = (ta-tb)/(1-ta*tb), r = 1/(1-ta*tb) > 0  -> tanh once per element
//   summand symmetric under i<->j   -> 2 * sum over unordered tri tile-pairs
//   (n*r)^signbit == (n^signbit)*r  (r>0, exact)  -> sign folds into the fma
//
// History: R8 (no atomics) 69.8us; R9 (768x512 grid, IT=8xJT=4, cross-job
// prefetch) 69.7us -> main loop is at/near its ~5.8us issue floor; remaining
// slack is launch/drain structure. R10: fuse the finalize into the main
// kernel via last-block-done. Counter lives in a module __device__ global
// (NOT d_ws -> never poisoned by the harness fill); "last of this launch"
// detected by old % 768 == 767 on a u64 counter, so no memset dispatch is
// needed. Last block replicates the old finalize's exact FP op order so the
// result stays bit-identical (absmax 0.0).

typedef float v2f __attribute__((ext_vector_type(2)));

#define TAU_N 1024
#define TAU_C 128
#define TILE  128
#define NTILE (TAU_N / TILE)              // 8
#define NTP   (NTILE * (NTILE + 1) / 2)   // 36 tile-pairs (ti >= tj) per column
#define BPC   6                           // blocks per column
#define JOBS  (NTP / BPC)                 // 6 jobs per block
#define PBLK  (TAU_C * BPC)               // 768 blocks (3 per CU)
#define THR   512                         // 8 waves per block
#define IT    8                           // i-elements per thread

__device__ __constant__ unsigned char c_TI[NTP] = {
    0,1,1,2,2,2,3,3,3,3,4,4,4,4,4,5,5,5,5,5,5,
    6,6,6,6,6,6,6,7,7,7,7,7,7,7,7};
__device__ __constant__ unsigned char c_TJ[NTP] = {
    0,0,1,0,1,2,0,1,2,3,0,1,2,3,4,0,1,2,3,4,5,
    0,1,2,3,4,5,6,0,1,2,3,4,5,6,7};
__device__ __constant__ float c_W[NTP] = {
    0.5f,1,0.5f,1,1,0.5f,1,1,1,0.5f,1,1,1,1,0.5f,1,1,1,1,1,0.5f,
    1,1,1,1,1,1,0.5f,1,1,1,1,1,1,1,0.5f};

// Module globals: survive across iterations, never touched by the d_ws poison
// fill. g_arrival grows by exactly PBLK per launch (stream-serialized), so
// old % PBLK == PBLK-1 identifies the last-arriving block of THIS launch.
__device__ float g_partials[PBLK];
__device__ unsigned long long g_arrival = 0ULL;

// 2 pairs: n = mt-tj; d = 1-mt*tj; ld = ml-lj; acc += (n^signbit(ld))*rcp(d)
__device__ __forceinline__ v2f tau_group(v2f m2, v2f mly, v2f t2, v2f l2, v2f acc) {
    const v2f one2 = {1.f, 1.f};
    v2f n  = m2 - t2;                                   // pk_sub
    v2f d  = __builtin_elementwise_fma(-m2, t2, one2);  // pk_fma
    v2f r  = {__builtin_amdgcn_rcpf(d.x), __builtin_amdgcn_rcpf(d.y)};
    v2f ld = mly - l2;                                  // pk_sub
    v2f ns = {__uint_as_float(__float_as_uint(n.x) ^
                              (__float_as_uint(ld.x) & 0x80000000u)),
              __uint_as_float(__float_as_uint(n.y) ^
                              (__float_as_uint(ld.y) & 0x80000000u))};
    return __builtin_elementwise_fma(ns, r, acc);       // pk_fma
}

__global__ __launch_bounds__(THR, 6) void tau_tri_kernel(
        const float* __restrict__ pred, const float* __restrict__ y,
        float* __restrict__ out) {
    __shared__ __align__(16) float ts[TAU_N];   // tanh(p)
    __shared__ __align__(16) float ys[TAU_N];   // y
    __shared__ float wsum[12];                  // 8 block-reduce + 12 finalize
    __shared__ int s_last;

    const int bx  = blockIdx.x;
    const int tid = threadIdx.x;
    const int c   = bx / BPC;
    const int jb0 = (bx % BPC) * JOBS;

    const float* p = pred + c * TAU_N;
    const float* l = y    + c * TAU_N;

    // Stage column (SoA): 2 elements per thread, one barrier.
    ts[tid]       = tanhf(p[tid]);
    ts[tid + THR] = tanhf(p[tid + THR]);
    ys[tid]       = l[tid];
    ys[tid + THR] = l[tid + THR];
    __syncthreads();

    const float4* t4 = (const float4*)ts;
    const float4* y4 = (const float4*)ys;
    const int ig = tid >> 5;                    // 16 i-groups of IT=8
    const int js = tid & 31;                    // 32 j-slices of 4 j

    // Prefetched LDS vectors for job q: 2x i-t, 2x i-y, 1x j-t, 1x j-y.
    float4 ta, tb, la, lb, tj4, yj4;
    {
        const int ti0 = c_TI[jb0], tj0 = c_TJ[jb0];
        const int ib4 = (ti0 * TILE + ig * IT) >> 2;
        const int jb4 = (tj0 * TILE + js * 4) >> 2;
        ta = t4[ib4]; tb = t4[ib4 + 1];
        la = y4[ib4]; lb = y4[ib4 + 1];
        tj4 = t4[jb4]; yj4 = y4[jb4];
    }

    float acc_tot = 0.f;

#pragma unroll
    for (int q = 0; q < JOBS; ++q) {
        const float w = c_W[jb0 + q];
        const float4 cta = ta, ctb = tb, cla = la, clb = lb;
        const float4 ctj = tj4, cyj = yj4;

        if (q + 1 < JOBS) {                     // prefetch next job's vectors
            const int tin = c_TI[jb0 + q + 1], tjn = c_TJ[jb0 + q + 1];
            const int ib4 = (tin * TILE + ig * IT) >> 2;
            const int jb4 = (tjn * TILE + js * 4) >> 2;
            ta = t4[ib4]; tb = t4[ib4 + 1];
            la = y4[ib4]; lb = y4[ib4 + 1];
            tj4 = t4[jb4]; yj4 = y4[jb4];
        }

        const v2f tA = {ctj.x, ctj.y}, tB = {ctj.z, ctj.w};
        const v2f lA = {cyj.x, cyj.y}, lB = {cyj.z, cyj.w};
        const float mt[IT] = {cta.x, cta.y, cta.z, cta.w, ctb.x, ctb.y, ctb.z, ctb.w};
        const float ml[IT] = {cla.x, cla.y, cla.z, cla.w, clb.x, clb.y, clb.z, clb.w};

        v2f a0 = {0.f,0.f}, a1 = {0.f,0.f}, a2 = {0.f,0.f}, a3 = {0.f,0.f};
#pragma unroll
        for (int a = 0; a < IT; ++a) {
            const v2f m2  = {mt[a], mt[a]};
            const v2f mly = {ml[a], ml[a]};
            if (a & 1) {
                a1 = tau_group(m2, mly, tA, lA, a1);
                a3 = tau_group(m2, mly, tB, lB, a3);
            } else {
                a0 = tau_group(m2, mly, tA, lA, a0);
                a2 = tau_group(m2, mly, tB, lB, a2);
            }
        }
        const v2f asum = (a0 + a1) + (a2 + a3);
        acc_tot = __builtin_fmaf(w, asum.x + asum.y, acc_tot);
    }

    // Block reduce: wave shfl tree -> cross-wave LDS -> per-block partial.
    for (int off = 32; off >= 1; off >>= 1)
        acc_tot += __shfl_down(acc_tot, off, 64);
    if ((tid & 63) == 0) wsum[tid >> 6] = acc_tot;
    __syncthreads();

    if (tid == 0) {
        float t = 0.f;
#pragma unroll
        for (int w = 0; w < THR / 64; ++w) t += wsum[w];
        // Publish partial (agent scope), release-fence, then arrive.
        __hip_atomic_store(&g_partials[bx], t, __ATOMIC_RELAXED,
                           __HIP_MEMORY_SCOPE_AGENT);
        __threadfence();
        unsigned long long old = atomicAdd(&g_arrival, 1ULL);
        s_last = ((old % (unsigned long long)PBLK) ==
                  (unsigned long long)(PBLK - 1)) ? 1 : 0;
    }
    __syncthreads();

    if (s_last) {
        // Last-arriving block of this launch: all 768 partials are published.
        // Replicate the old finalize kernel's exact FP op order:
        //   12 virtual waves, each a 64-lane shfl tree over values [64w,64w+63],
        //   then a sequential 12-term sum.
        __threadfence();   // acquire side
        float v0 = __hip_atomic_load(&g_partials[tid], __ATOMIC_RELAXED,
                                     __HIP_MEMORY_SCOPE_AGENT);
        for (int off = 32; off >= 1; off >>= 1)
            v0 += __shfl_down(v0, off, 64);
        if ((tid & 63) == 0) wsum[tid >> 6] = v0;        // slots 0..7

        float v1 = 0.f;
        if (tid < 256)
            v1 = __hip_atomic_load(&g_partials[THR + tid], __ATOMIC_RELAXED,
                                   __HIP_MEMORY_SCOPE_AGENT);
        for (int off = 32; off >= 1; off >>= 1)
            v1 += __shfl_down(v1, off, 64);
        if (tid < 256 && (tid & 63) == 0) wsum[8 + (tid >> 6)];  // placeholder
        if (tid < 256 && (tid & 63) == 0) wsum[8 + (tid >> 6)] = v1; // slots 8..11
        __syncthreads();

        if (tid == 0) {
            float t = 0.f;
#pragma unroll
            for (int w = 0; w < 12; ++w) t += wsum[w];
            const float scale =
                2.0f / ((float)TAU_N * (float)(TAU_N - 1) * (float)TAU_C);
            out[0] = 1.0f - t * scale;
        }
    }
}

extern "C" void kernel_launch(void* const* d_in, const int* in_sizes, int n_in,
                              void* d_out, int out_size, void* d_ws, size_t ws_size,
                              hipStream_t stream) {
    const float* pred = (const float*)d_in[0];
    const float* y    = (const float*)d_in[1];
    float* out        = (float*)d_out;
    (void)d_ws; (void)ws_size;

    tau_tri_kernel<<<PBLK, THR, 0, stream>>>(pred, y, out);
}

// Round 2
// 70.065 us; speedup vs baseline: 1.0887x; 1.0887x over previous
//
#include <hip/hip_runtime.h>

// TauLoss: 1 - mean_c [ sum_{i,j} sign(y[c,i]-y[c,j]) * tanh(p[c,i]-p[c,j]) / (N*(N-1)) ]
//
// Identities:
//   tanh(d*s) = s*tanh(d), s in {-1,0,1}
//   tanh(a-b) = (ta-tb)/(1-ta*tb), r = 1/(1-ta*tb) > 0  -> tanh once per element
//   summand symmetric under i<->j   -> 2 * sum over unordered tri tile-pairs
//   s*r == +-r exactly (r>0, never denormal) -> sign folds via one pk_mul
//
// History:
//   R8  69.8us: no atomics (plain partials store + tiny finalize kernel).
//       ~53us immovable harness floor (256MB d_ws poison fill ~40us etc.)
//       + ~17us kernel-side.
//   R9  69.7us: 768x512 grid (3 blocks/CU, zero drain tail), IT=8xJT=4,
//       cross-job LDS prefetch. Main loop at ~VALU issue floor.
//   R10 76.3us FAILED: fused last-block-done finalize. Agent-scope
//       __threadfence() on 8-XCD part (buffer_wbl2-class cost) x768 blocks
//       + cross-XCD acquire reads + tail serialization cost ~6.6us > the
//       ~2-3us launch gap it removed. Two-kernel structure is correct.
//   R11: revert to R9 structure; inner loop sign-fold 8->7 VALU per 2 pairs:
//       s = +-1.0 via v_and_or_b32 (1 op/pair), fold via v_pk_mul_f32.
//       Bit-identical FP path (s*r == +-r exactly).

typedef float v2f __attribute__((ext_vector_type(2)));

#define TAU_N 1024
#define TAU_C 128
#define TILE  128
#define NTILE (TAU_N / TILE)              // 8
#define NTP   (NTILE * (NTILE + 1) / 2)   // 36 tile-pairs (ti >= tj) per column
#define BPC   6                           // blocks per column
#define JOBS  (NTP / BPC)                 // 6 jobs per block
#define PBLK  (TAU_C * BPC)               // 768 blocks (3 per CU)
#define THR   512                         // 8 waves per block
#define IT    8                           // i-elements per thread

__device__ __constant__ unsigned char c_TI[NTP] = {
    0,1,1,2,2,2,3,3,3,3,4,4,4,4,4,5,5,5,5,5,5,
    6,6,6,6,6,6,6,7,7,7,7,7,7,7,7};
__device__ __constant__ unsigned char c_TJ[NTP] = {
    0,0,1,0,1,2,0,1,2,3,0,1,2,3,4,0,1,2,3,4,5,
    0,1,2,3,4,5,6,0,1,2,3,4,5,6,7};
__device__ __constant__ float c_W[NTP] = {
    0.5f,1,0.5f,1,1,0.5f,1,1,1,0.5f,1,1,1,1,0.5f,1,1,1,1,1,0.5f,
    1,1,1,1,1,1,0.5f,1,1,1,1,1,1,1,0.5f};

// 2 pairs: n = mt-tj; d = 1-mt*tj; ld = ml-lj;
//          s = +-1.0 (signbit of ld);  acc += n * (s*r)
// v_and_or_b32 builds s in ONE op/pair; pk_mul folds the sign for both
// pairs at once. s*r is exactly +-r (r in (0.5, inf), never denormal), so
// fma(n, s*r, acc) is bit-identical to the previous fma(n^signbit, r, acc).
__device__ __forceinline__ v2f tau_group(v2f m2, v2f mly, v2f t2, v2f l2, v2f acc) {
    const v2f one2 = {1.f, 1.f};
    v2f n  = m2 - t2;                                   // pk_sub
    v2f d  = __builtin_elementwise_fma(-m2, t2, one2);  // pk_fma
    v2f r  = {__builtin_amdgcn_rcpf(d.x), __builtin_amdgcn_rcpf(d.y)};
    v2f ld = mly - l2;                                  // pk_sub
    v2f s  = {__uint_as_float((__float_as_uint(ld.x) & 0x80000000u) | 0x3f800000u),
              __uint_as_float((__float_as_uint(ld.y) & 0x80000000u) | 0x3f800000u)};
    v2f sr = s * r;                                     // pk_mul (exactly +-r)
    return __builtin_elementwise_fma(n, sr, acc);       // pk_fma
}

__global__ __launch_bounds__(THR, 6) void tau_tri_kernel(
        const float* __restrict__ pred, const float* __restrict__ y,
        float* __restrict__ partials) {
    __shared__ __align__(16) float ts[TAU_N];   // tanh(p)
    __shared__ __align__(16) float ys[TAU_N];   // y
    __shared__ float wsum[THR / 64];

    const int bx  = blockIdx.x;
    const int tid = threadIdx.x;
    const int c   = bx / BPC;
    const int jb0 = (bx % BPC) * JOBS;

    const float* p = pred + c * TAU_N;
    const float* l = y    + c * TAU_N;

    // Stage column (SoA): 2 elements per thread, one barrier.
    ts[tid]       = tanhf(p[tid]);
    ts[tid + THR] = tanhf(p[tid + THR]);
    ys[tid]       = l[tid];
    ys[tid + THR] = l[tid + THR];
    __syncthreads();

    const float4* t4 = (const float4*)ts;
    const float4* y4 = (const float4*)ys;
    const int ig = tid >> 5;                    // 16 i-groups of IT=8
    const int js = tid & 31;                    // 32 j-slices of 4 j

    // Prefetched LDS vectors for job q: 2x i-t, 2x i-y, 1x j-t, 1x j-y.
    float4 ta, tb, la, lb, tj4, yj4;
    {
        const int ti0 = c_TI[jb0], tj0 = c_TJ[jb0];
        const int ib4 = (ti0 * TILE + ig * IT) >> 2;
        const int jb4 = (tj0 * TILE + js * 4) >> 2;
        ta = t4[ib4]; tb = t4[ib4 + 1];
        la = y4[ib4]; lb = y4[ib4 + 1];
        tj4 = t4[jb4]; yj4 = y4[jb4];
    }

    float acc_tot = 0.f;

#pragma unroll
    for (int q = 0; q < JOBS; ++q) {
        const float w = c_W[jb0 + q];
        const float4 cta = ta, ctb = tb, cla = la, clb = lb;
        const float4 ctj = tj4, cyj = yj4;

        if (q + 1 < JOBS) {                     // prefetch next job's vectors
            const int tin = c_TI[jb0 + q + 1], tjn = c_TJ[jb0 + q + 1];
            const int ib4 = (tin * TILE + ig * IT) >> 2;
            const int jb4 = (tjn * TILE + js * 4) >> 2;
            ta = t4[ib4]; tb = t4[ib4 + 1];
            la = y4[ib4]; lb = y4[ib4 + 1];
            tj4 = t4[jb4]; yj4 = y4[jb4];
        }

        const v2f tA = {ctj.x, ctj.y}, tB = {ctj.z, ctj.w};
        const v2f lA = {cyj.x, cyj.y}, lB = {cyj.z, cyj.w};
        const float mt[IT] = {cta.x, cta.y, cta.z, cta.w, ctb.x, ctb.y, ctb.z, ctb.w};
        const float ml[IT] = {cla.x, cla.y, cla.z, cla.w, clb.x, clb.y, clb.z, clb.w};

        v2f a0 = {0.f,0.f}, a1 = {0.f,0.f}, a2 = {0.f,0.f}, a3 = {0.f,0.f};
#pragma unroll
        for (int a = 0; a < IT; ++a) {
            const v2f m2  = {mt[a], mt[a]};
            const v2f mly = {ml[a], ml[a]};
            if (a & 1) {
                a1 = tau_group(m2, mly, tA, lA, a1);
                a3 = tau_group(m2, mly, tB, lB, a3);
            } else {
                a0 = tau_group(m2, mly, tA, lA, a0);
                a2 = tau_group(m2, mly, tB, lB, a2);
            }
        }
        const v2f asum = (a0 + a1) + (a2 + a3);
        acc_tot = __builtin_fmaf(w, asum.x + asum.y, acc_tot);
    }

    // Wave reduce -> cross-wave LDS -> ONE plain store per block. No atomics.
    for (int off = 32; off >= 1; off >>= 1)
        acc_tot += __shfl_down(acc_tot, off, 64);
    if ((tid & 63) == 0) wsum[tid >> 6] = acc_tot;
    __syncthreads();
    if (tid == 0) {
        float t = 0.f;
#pragma unroll
        for (int w = 0; w < THR / 64; ++w) t += wsum[w];
        partials[bx] = t;
    }
}

__global__ __launch_bounds__(PBLK) void tau_finalize_kernel(
        const float* __restrict__ partials, float* __restrict__ out) {
    __shared__ float wsum[PBLK / 64];
    const int tid = threadIdx.x;               // PBLK = 768 threads
    float acc = partials[tid];
    for (int off = 32; off >= 1; off >>= 1)
        acc += __shfl_down(acc, off, 64);
    if ((tid & 63) == 0) wsum[tid >> 6] = acc;
    __syncthreads();
    if (tid == 0) {
        float t = 0.f;
#pragma unroll
        for (int w = 0; w < PBLK / 64; ++w) t += wsum[w];
        const float scale = 2.0f / ((float)TAU_N * (float)(TAU_N - 1) * (float)TAU_C);
        out[0] = 1.0f - t * scale;
    }
}

extern "C" void kernel_launch(void* const* d_in, const int* in_sizes, int n_in,
                              void* d_out, int out_size, void* d_ws, size_t ws_size,
                              hipStream_t stream) {
    const float* pred = (const float*)d_in[0];
    const float* y    = (const float*)d_in[1];
    float* out        = (float*)d_out;
    float* partials   = (float*)d_ws;   // PBLK floats; each written exactly once

    tau_tri_kernel<<<PBLK, THR, 0, stream>>>(pred, y, partials);
    tau_finalize_kernel<<<1, PBLK, 0, stream>>>(partials, out);
}